// Round 12
// baseline (1386.345 us; speedup 1.0000x reference)
//
#include <hip/hip_runtime.h>
#include <hip/hip_bf16.h>

// R17 = R13 verbatim (verified PASS @ 1361us total, fused 1246us). The R14-R16
// arc (xp0 folded into workers, +same-XCD exchange fast path) NaN'd 3x with an
// un-localized bug in the 3-way producer/consumer schedule; reverting to the
// best verified kernel.
// R13: fused pipeline -- blocks 0-15 L0 recurrence (R9 split-K step structure),
// blocks 16-31 L1 recurrence, blocks 32+ persistent GEMM workers computing
// xp1 = out0 @ Wih1^T tiles as L0 produces out0 rows. Cross-block dataflow via
// L3-resident rings (out0 64 rows, xp1 32 rows, packed (col,col+16) dwords,
// agent-scope atomics); readiness via monotonic counters/flags ordered by each
// wave's vmcnt(0)+barrier. Worker contention fixes: gate spins wave-0-only,
// vectorized dwordx4 ring staging, NWORKER=64.

typedef __attribute__((ext_vector_type(8))) short bf16x8;
typedef __attribute__((ext_vector_type(4))) short bf16x4;
typedef __attribute__((ext_vector_type(4))) float f32x4;
typedef __attribute__((ext_vector_type(4))) unsigned int u32x4;

#define T_STEPS 512
#define NBATCH  128
#define HID     512
#define INSZ    256
#define HB      8192      // shorts per LDS h buffer (16 samples x 512 cols, frag-major)
#define R0SLOTS 64        // out0 ring rows
#define R1SLOTS 32        // xp1 ring rows
#define EX_WORDS 131072   // 8 gb x 2 slot x 2 p x 4096
#define NWORKER 64

static __device__ __forceinline__ float bf2f(__hip_bfloat16 v) { return __bfloat162float(v); }
static __device__ __forceinline__ __hip_bfloat16 f2bf(float v) { return __float2bfloat16(v); }

union BF8 { bf16x8 v; unsigned short u[8]; };
union BF4 { bf16x4 v; unsigned short u[4]; };
static __device__ __forceinline__ unsigned short f2bfbits(float x) {
    __hip_bfloat16 b = __float2bfloat16(x);
    return *reinterpret_cast<unsigned short*>(&b);
}
static __device__ __forceinline__ float bfbits2f(unsigned short us) {
    return bf2f(*reinterpret_cast<__hip_bfloat16*>(&us));
}
static __device__ __forceinline__ float loadE(const void* p, size_t i, bool f32) {
    return f32 ? ((const float*)p)[i] : bf2f(((const __hip_bfloat16*)p)[i]);
}
// tanh(x) = 1 - 2/(e^{2x}+1); exp over/underflow saturates correctly to +-1.
static __device__ __forceinline__ float fast_tanh(float x) {
    float e = __expf(2.f * x);
    float r = __builtin_amdgcn_rcpf(e + 1.f);
    return 1.f - 2.f * r;
}
static __device__ __forceinline__ unsigned int aload(const unsigned int* p) {
    return __hip_atomic_load(p, __ATOMIC_RELAXED, __HIP_MEMORY_SCOPE_AGENT);
}
static __device__ __forceinline__ void astore(unsigned int* p, unsigned int v) {
    __hip_atomic_store(p, v, __ATOMIC_RELAXED, __HIP_MEMORY_SCOPE_AGENT);
}
// coherent reload + full drain (retry path only)
static __device__ __forceinline__ void load2_coherent(const unsigned int* p, u32x4& a, u32x4& b) {
    asm volatile("global_load_dwordx4 %0, %2, off sc0 sc1\n\t"
                 "global_load_dwordx4 %1, %3, off sc0 sc1\n\t"
                 "s_waitcnt vmcnt(0)"
                 : "=&v"(a), "=&v"(b)
                 : "v"(p), "v"(p + 4)
                 : "memory");
}
// issue poll loads early (no wait)
static __device__ __forceinline__ void pollIssue(const unsigned int* p, u32x4& a, u32x4& b) {
    asm volatile("global_load_dwordx4 %0, %2, off sc0 sc1\n\t"
                 "global_load_dwordx4 %1, %3, off sc0 sc1"
                 : "=&v"(a), "=&v"(b)
                 : "v"(p), "v"(p + 4)
                 : "memory");
}
// full-drain wait; consumers data-depend on in-out operands (rule-18 safe)
static __device__ __forceinline__ void pollWait(u32x4& a, u32x4& b) {
    asm volatile("s_waitcnt vmcnt(0)" : "+v"(a), "+v"(b) :: "memory");
}
// coherent 16B ring load: issue-only + wait-later pair
static __device__ __forceinline__ void ringIssue(const unsigned int* p, u32x4& w) {
    asm volatile("global_load_dwordx4 %0, %1, off sc0 sc1"
                 : "=&v"(w) : "v"(p) : "memory");
}
static __device__ __forceinline__ void ringWait(u32x4& w) {
    asm volatile("s_waitcnt vmcnt(0)" : "+v"(w) :: "memory");
}

// ---------------- dtype probe
__global__ void detect_dtype(const unsigned short* __restrict__ x, unsigned int* __restrict__ dflag) {
    if (threadIdx.x == 0 && blockIdx.x == 0) {
        int sane = 0;
        for (int i = 0; i < 64; ++i) {
            unsigned short v = x[2 * i];
            unsigned int e = (v >> 7) & 0xFF;
            if (v == 0 || (e >= 0x60 && e <= 0x9F)) ++sane;
        }
        *dflag = (sane >= 48) ? 0u : 1u;  // 0 = bf16 data, 1 = fp32 data
    }
}

// ---------------- GEMM: out[M][N] = A[M][K] @ W[N][K]^T + b1[N] (+ b2[N])
__global__ __launch_bounds__(256, 4) void gemm_bt64(
    const void* __restrict__ A, const void* __restrict__ W,
    const void* __restrict__ b1, const void* __restrict__ b2,
    void* __restrict__ out, int M, int N, int K,
    const int* __restrict__ lengths, const unsigned int* __restrict__ dflag,
    int aIsOrig, int outIsOutput)
{
    const int r0 = blockIdx.y * 64;
    if (lengths) {
        int t = r0 >> 7, n0 = r0 & 127;
        if (lengths[n0] <= t) return;
    }
    const bool f32 = *dflag != 0;
    const int c0 = blockIdx.x * 64;
    __shared__ short As[64 * 32];
    __shared__ short Bs[64 * 32];
    const int tid = threadIdx.x;
    const int lane = tid & 63, wave = tid >> 6;
    const int lrow = tid >> 2, lk = (tid & 3) * 8;
    const int q = (lane >> 4) & 3, l15 = lane & 15;

    f32x4 z = {0.f, 0.f, 0.f, 0.f};
    f32x4 acc[4];
#pragma unroll
    for (int m = 0; m < 4; ++m) acc[m] = z;

    for (int kk = 0; kk < K; kk += 32) {
        if (aIsOrig && f32) {
            const float* f = (const float*)A + (size_t)(r0 + lrow) * K + kk + lk;
            BF8 u;
#pragma unroll
            for (int i = 0; i < 8; ++i) u.u[i] = f2bfbits(f[i]);
            *(bf16x8*)&As[lrow * 32 + lk] = u.v;
        } else {
            *(bf16x8*)&As[lrow * 32 + lk] =
                *(const bf16x8*)((const __hip_bfloat16*)A + (size_t)(r0 + lrow) * K + kk + lk);
        }
        if (f32) {
            const float* f = (const float*)W + (size_t)(c0 + lrow) * K + kk + lk;
            BF8 u;
#pragma unroll
            for (int i = 0; i < 8; ++i) u.u[i] = f2bfbits(f[i]);
            *(bf16x8*)&Bs[lrow * 32 + lk] = u.v;
        } else {
            *(bf16x8*)&Bs[lrow * 32 + lk] =
                *(const bf16x8*)((const __hip_bfloat16*)W + (size_t)(c0 + lrow) * K + kk + lk);
        }
        __syncthreads();
        bf16x8 bfrag = *(const bf16x8*)&Bs[(wave * 16 + l15) * 32 + q * 8];
#pragma unroll
        for (int m = 0; m < 4; ++m) {
            bf16x8 afrag = *(const bf16x8*)&As[(m * 16 + l15) * 32 + q * 8];
            acc[m] = __builtin_amdgcn_mfma_f32_16x16x32_bf16(afrag, bfrag, acc[m], 0, 0, 0);
        }
        __syncthreads();
    }
    const int col = c0 + wave * 16 + l15;
    float bias = loadE(b1, col, f32) + (b2 ? loadE(b2, col, f32) : 0.f);
#pragma unroll
    for (int m = 0; m < 4; ++m) {
#pragma unroll
        for (int r = 0; r < 4; ++r) {
            int row = r0 + m * 16 + q * 4 + r;
            float v = acc[m][r] + bias;
            if (outIsOutput && f32) ((float*)out)[(size_t)row * N + col] = v;
            else ((__hip_bfloat16*)out)[(size_t)row * N + col] = f2bf(v);
        }
    }
}

// ---------------- recurrence role (R9 step structure + ring/flag deltas)
static __device__ void recur_role(
    int rbid, int tid, short* hlds,
    const __hip_bfloat16* __restrict__ xp0,
    const void* __restrict__ Whh, const void* __restrict__ h0all, int layer,
    const int* __restrict__ lengths,
    unsigned int* __restrict__ outring, unsigned int* __restrict__ xp1ring,
    void* __restrict__ hout, int houtOff, __hip_bfloat16* __restrict__ hfbf,
    unsigned int* __restrict__ ex, const unsigned int* __restrict__ dflag,
    unsigned int* __restrict__ c0w, unsigned int* __restrict__ F,
    unsigned int* __restrict__ c1w)
{
    const int gb = rbid & 7, p = (rbid >> 3) & 1;
    const int lane = tid & 63, wave = tid >> 6;
    const int q = (lane >> 4) & 3, l15 = lane & 15;
    const int colBase = p * 256 + wave * 32;
    const int s0 = gb * 16;
    const int nh = gb >> 2;
    const int pcPart = (1 - p) * 256;
    const int Dr = p * 128 + wave * 16 + l15;   // ring dword index (cols c, c+16)
    const bool f32 = *dflag != 0;
    const size_t h0base = (size_t)layer * NBATCH * HID;

    // persistent B fragments, STATIC indices only (rule #20)
    bf16x8 bfr_own[2][8], bfr_par[2][8];
    {
        const int kbO = p * 256, kbP = (1 - p) * 256;
#pragma unroll
        for (int tau = 0; tau < 2; ++tau) {
            const size_t jrow = (size_t)(colBase + tau * 16 + l15) * HID;
            if (f32) {
#pragma unroll
                for (int c8 = 0; c8 < 8; ++c8) {
                    const float* fo = (const float*)Whh + jrow + kbO + c8 * 32 + q * 8;
                    const float* fp = (const float*)Whh + jrow + kbP + c8 * 32 + q * 8;
                    BF8 uo, up;
#pragma unroll
                    for (int i = 0; i < 8; ++i) { uo.u[i] = f2bfbits(fo[i]); up.u[i] = f2bfbits(fp[i]); }
                    bfr_own[tau][c8] = uo.v; bfr_par[tau][c8] = up.v;
                }
            } else {
#pragma unroll
                for (int c8 = 0; c8 < 8; ++c8) {
                    bfr_own[tau][c8] = *(const bf16x8*)((const __hip_bfloat16*)Whh + jrow + kbO + c8 * 32 + q * 8);
                    bfr_par[tau][c8] = *(const bf16x8*)((const __hip_bfloat16*)Whh + jrow + kbP + c8 * 32 + q * 8);
                }
            }
        }
    }

    int len_r[4];
#pragma unroll
    for (int r = 0; r < 4; ++r) len_r[r] = lengths[s0 + q * 4 + r];

    float cur[2][4];
#pragma unroll
    for (int tau = 0; tau < 2; ++tau)
#pragma unroll
        for (int r = 0; r < 4; ++r)
            cur[tau][r] = loadE(h0all, h0base + (size_t)(s0 + q * 4 + r) * HID + colBase + tau * 16 + l15, f32);

    // stage FULL S_0 into LDS buf 0 (frag-major)
    {
        const int sr = tid >> 5, cb16 = (tid & 31) * 16;
        BF8 u0, u1;
#pragma unroll
        for (int i = 0; i < 8; ++i) {
            u0.u[i] = f2bfbits(loadE(h0all, h0base + (size_t)(s0 + sr) * HID + cb16 + i, f32));
            u1.u[i] = f2bfbits(loadE(h0all, h0base + (size_t)(s0 + sr) * HID + cb16 + 8 + i, f32));
        }
        *(bf16x8*)&hlds[(((cb16 >> 3) * 16) + sr) * 8] = u0.v;
        *(bf16x8*)&hlds[((((cb16 + 8) >> 3) * 16) + sr) * 8] = u1.v;
    }
    __syncthreads();

    const int Tg = lengths[s0];
    const int psr = tid >> 5;
    const int pwc = (tid * 8) & 255;
    unsigned int* exg = ex + (size_t)gb * 2 * 2 * 4096;

    // xp prologue (row 0)
    float xv[2][4];
    unsigned int l1flag = 0;
    if (layer == 0) {
        const __hip_bfloat16* xprow = xp0 + (size_t)s0 * HID;
#pragma unroll
        for (int tau = 0; tau < 2; ++tau)
#pragma unroll
            for (int r = 0; r < 4; ++r)
                xv[tau][r] = bf2f(xprow[(size_t)(q * 4 + r) * HID + colBase + tau * 16 + l15]);
    } else {
        const unsigned int* fp = &F[(size_t)nh * 2 + p];   // row 0 flag
        int spins = 0;
        while (aload(fp) != 1u) {
            __builtin_amdgcn_s_sleep(2);
            if (++spins > (1 << 20)) break;
        }
#pragma unroll
        for (int r = 0; r < 4; ++r) {
            unsigned int u = aload(&xp1ring[((size_t)(s0 + q * 4 + r)) * 256 + Dr]);
            xv[0][r] = bfbits2f((unsigned short)(u & 0xffffu));
            xv[1][r] = bfbits2f((unsigned short)(u >> 16));
        }
        if (1 < Tg) l1flag = aload(&F[(size_t)1 * 4 + nh * 2 + p]);
    }

    for (int t = 0; t < Tg; ++t) {
        const int cb = t & 1, nb = (t + 1) & 1;
        short* hrd = &hlds[cb * HB];
        short* hwr = &hlds[nb * HB];
        const unsigned int ptag = (unsigned int)t;

        // L0 back-pressure on out0 ring (amortized; wave 0 only, sync1 fences)
        if (layer == 0 && t >= R0SLOTS && (t & 15) == 0 && wave == 0) {
            const int row = t - R0SLOTS + ((lane >> 1) & 15);
            const unsigned int* fp = &F[(size_t)row * 4 + nh * 2 + (lane & 1)];
            const unsigned int expv = (unsigned int)(row + 1);
            int spins = 0;
            while (!__all((int)(aload(fp) == expv))) {
                __builtin_amdgcn_s_sleep(2);
                if (++spins > (1 << 20)) break;
            }
        }

        // xp prefetch for row t+1
        float xn[2][4];
        unsigned int xnu[4];
        if (t + 1 < Tg) {
            if (layer == 0) {
                const __hip_bfloat16* xprow = xp0 + ((size_t)(t + 1) * NBATCH + s0) * HID;
#pragma unroll
                for (int tau = 0; tau < 2; ++tau)
#pragma unroll
                    for (int r = 0; r < 4; ++r)
                        xn[tau][r] = bf2f(xprow[(size_t)(q * 4 + r) * HID + colBase + tau * 16 + l15]);
            } else {
                const unsigned int expv = (unsigned int)(t + 2);
                if (l1flag != expv) {
                    const unsigned int* fp = &F[(size_t)(t + 1) * 4 + nh * 2 + p];
                    int spins = 0;
                    while (aload(fp) != expv) {
                        __builtin_amdgcn_s_sleep(1);
                        if (++spins > (1 << 20)) break;
                    }
                }
                const size_t rb = ((size_t)((t + 1) % R1SLOTS) * 128 + s0) * 256;
#pragma unroll
                for (int r = 0; r < 4; ++r)
                    xnu[r] = aload(&xp1ring[rb + (size_t)(q * 4 + r) * 256 + Dr]);
            }
        }

        // poll loads for partner half of S_t
        const unsigned int* exr = exg + ((size_t)cb * 2 + (1 - p)) * 4096 + tid * 8;
        u32x4 va, vb;
        if (t > 0) pollIssue(exr, va, vb);

        f32x4 zz = {0.f, 0.f, 0.f, 0.f};
        f32x4 acc[2] = {zz, zz};

        // (a) own k-half MFMA
        {
            const int cO = p * 8;
#pragma unroll
            for (int c8 = 0; c8 < 8; ++c8) {
                bf16x8 a = *(const bf16x8*)&hrd[(((cO + c8) * 4 + q) * 16 + l15) * 8];
                acc[0] = __builtin_amdgcn_mfma_f32_16x16x32_bf16(a, bfr_own[0][c8], acc[0], 0, 0, 0);
                acc[1] = __builtin_amdgcn_mfma_f32_16x16x32_bf16(a, bfr_own[1][c8], acc[1], 0, 0, 0);
            }
        }

        // (b) poll partner's half of S_t; write into hrd partner region
        if (t > 0) {
            pollWait(va, vb);
            int spins = 0;
            for (;;) {
                bool ok = (va[0] >> 16) == ptag && (va[1] >> 16) == ptag &&
                          (va[2] >> 16) == ptag && (va[3] >> 16) == ptag &&
                          (vb[0] >> 16) == ptag && (vb[1] >> 16) == ptag &&
                          (vb[2] >> 16) == ptag && (vb[3] >> 16) == ptag;
                if (ok) break;
                if (++spins > 4) __builtin_amdgcn_s_sleep(1);
                if (spins > (1 << 20)) break;
                load2_coherent(exr, va, vb);
            }
            BF8 u;
            u.u[0] = (unsigned short)(va[0] & 0xFFFF); u.u[1] = (unsigned short)(va[1] & 0xFFFF);
            u.u[2] = (unsigned short)(va[2] & 0xFFFF); u.u[3] = (unsigned short)(va[3] & 0xFFFF);
            u.u[4] = (unsigned short)(vb[0] & 0xFFFF); u.u[5] = (unsigned short)(vb[1] & 0xFFFF);
            u.u[6] = (unsigned short)(vb[2] & 0xFFFF); u.u[7] = (unsigned short)(vb[3] & 0xFFFF);
            const int jp = pcPart + pwc;
            *(bf16x8*)&hrd[((jp >> 3) * 16 + psr) * 8] = u.v;
        }
        __syncthreads();   // sync1

        // progress publish (ordering: every wave's (b) vmcnt(0) + barrier above)
        if (t > 0 && tid == 0) {
            if (layer == 0) astore(&c0w[gb * 2 + p], (unsigned int)t);
            else            astore(&c1w[gb * 2 + p], (unsigned int)(t + 2));
        }
        if (layer == 1 && t + 2 < Tg)
            l1flag = aload(&F[(size_t)(t + 2) * 4 + nh * 2 + p]);

        // (c) partner k-half MFMA
        {
            const int cP = (1 - p) * 8;
#pragma unroll
            for (int c8 = 0; c8 < 8; ++c8) {
                bf16x8 a = *(const bf16x8*)&hrd[(((cP + c8) * 4 + q) * 16 + l15) * 8];
                acc[0] = __builtin_amdgcn_mfma_f32_16x16x32_bf16(a, bfr_par[0][c8], acc[0], 0, 0, 0);
                acc[1] = __builtin_amdgcn_mfma_f32_16x16x32_bf16(a, bfr_par[1][c8], acc[1], 0, 0, 0);
            }
        }

        // (d) tanh; publish own half of S_{t+1}; out0 ring (layer 0); LDS h write
        const unsigned int tag = (unsigned int)(t + 1);
        unsigned int* exw = exg + ((size_t)nb * 2 + p) * 4096;
        unsigned short bits[2][4];
#pragma unroll
        for (int tau = 0; tau < 2; ++tau)
#pragma unroll
            for (int r = 0; r < 4; ++r) {
                float hnew = fast_tanh(acc[tau][r] + xv[tau][r]);
                float val = (t < len_r[r]) ? hnew : cur[tau][r];
                cur[tau][r] = val;
                bits[tau][r] = f2bfbits(val);
                if (t + 1 < Tg)
                    __hip_atomic_store(&exw[(q * 4 + r) * 256 + wave * 32 + tau * 16 + l15],
                                       (tag << 16) | (unsigned int)bits[tau][r],
                                       __ATOMIC_RELAXED, __HIP_MEMORY_SCOPE_AGENT);
            }
        if (layer == 0) {
            const size_t rb = ((size_t)(t % R0SLOTS) * 128 + s0) * 256;
#pragma unroll
            for (int r = 0; r < 4; ++r) {
                unsigned int pk = (unsigned int)bits[0][r] | ((unsigned int)bits[1][r] << 16);
                astore(&outring[rb + (size_t)(q * 4 + r) * 256 + Dr], pk);
            }
        }
#pragma unroll
        for (int tau = 0; tau < 2; ++tau)
#pragma unroll
            for (int r = 0; r < 4; ++r) {
                const int sl = q * 4 + r;
                const int j = colBase + tau * 16 + l15;
                hwr[((j >> 3) * 16 + sl) * 8 + (j & 7)] = (short)bits[tau][r];
            }
        __syncthreads();   // sync2

        if (t + 1 < Tg) {
            if (layer == 0) {
#pragma unroll
                for (int tau = 0; tau < 2; ++tau)
#pragma unroll
                    for (int r = 0; r < 4; ++r) xv[tau][r] = xn[tau][r];
            } else {
#pragma unroll
                for (int r = 0; r < 4; ++r) {
                    xv[0][r] = bfbits2f((unsigned short)(xnu[r] & 0xffffu));
                    xv[1][r] = bfbits2f((unsigned short)(xnu[r] >> 16));
                }
            }
        }
    }

    // finalize counters (rows all at coherence point)
    asm volatile("s_waitcnt vmcnt(0)" ::: "memory");
    __syncthreads();
    if (tid == 0) {
        if (layer == 0) astore(&c0w[gb * 2 + p], 1u << 20);
        else            astore(&c1w[gb * 2 + p], 1u << 20);
    }

    // finals: h to d_out + bf16 copy for logits GEMM
#pragma unroll
    for (int tau = 0; tau < 2; ++tau)
#pragma unroll
        for (int r = 0; r < 4; ++r) {
            size_t idx = (size_t)(s0 + q * 4 + r) * HID + colBase + tau * 16 + l15;
            if (f32) ((float*)hout)[houtOff + idx] = cur[tau][r];
            else     ((__hip_bfloat16*)hout)[houtOff + idx] = f2bf(cur[tau][r]);
            hfbf[idx] = f2bf(cur[tau][r]);
        }
}

// ---------------- worker role: xp1 tiles (64 rows x 256 cols), streaming K
static __device__ void worker_role(
    int wid, int tid, short* smem,
    const void* __restrict__ Wih1, const void* __restrict__ b1, const void* __restrict__ b2,
    const int* __restrict__ lengths,
    unsigned int* __restrict__ outring, unsigned int* __restrict__ xp1ring,
    const unsigned int* __restrict__ dflag,
    unsigned int* __restrict__ c0w, unsigned int* __restrict__ F,
    unsigned int* __restrict__ c1w)
{
    const bool f32 = *dflag != 0;
    const int lane = tid & 63, wave = tid >> 6;
    const int q = (lane >> 4) & 3, l15 = lane & 15;
    short* As = smem;           // 64 x 32
    short* Bs = smem + 2048;    // 256 x 32
    const int len0 = lengths[0], len64 = lengths[64];

    for (int lin = wid; lin < T_STEPS * 4; lin += NWORKER) {
        const int t = lin >> 2, nh = (lin >> 1) & 1, ph = lin & 1;
        const int lenh = nh ? len64 : len0;
        if (lenh <= t) continue;   // dead tile (uniform)

        // ready gate: wave 0 spins; other waves wait at the barrier
        if (wave == 0) {
            const int gbase = nh * 4;
            int spins = 0;
            for (;;) {
                bool ok = true;
#pragma unroll
                for (int g = 0; g < 4; ++g) {
                    ok = ok && ((int)aload(&c0w[(gbase + g) * 2 + 0]) >= t + 1);
                    ok = ok && ((int)aload(&c0w[(gbase + g) * 2 + 1]) >= t + 1);
                }
                if (t >= R1SLOTS) {
#pragma unroll
                    for (int g = 0; g < 4; ++g)
                        ok = ok && ((int)aload(&c1w[(gbase + g) * 2 + ph]) >= t - R1SLOTS + 1);
                }
                if (ok) break;
                __builtin_amdgcn_s_sleep(8);
                if (++spins > (1 << 20)) break;
            }
        }
        __syncthreads();

        f32x4 z = {0.f, 0.f, 0.f, 0.f};
        f32x4 acc[2][4];
#pragma unroll
        for (int tau = 0; tau < 2; ++tau)
#pragma unroll
            for (int m = 0; m < 4; ++m) acc[tau][m] = z;

        const size_t srcBase = ((size_t)(t % R0SLOTS) * 128 + nh * 64) * 256;
        const int arow = tid >> 2, aj = tid & 3;   // As staging map (tid<256)

        for (int kk = 0; kk < HID; kk += 32) {
            // As: issue ONE contiguous dwordx4 per thread (16 dwords per row =
            // the full 32-col chunk; lo half = cols kk+c15, hi = kk+16+c15)
            u32x4 wv;
            if (tid < 256) {   // waves 0-3 (wave-uniform branch)
                const int Dbase = ((kk >> 8) * 128) + (((kk >> 5) & 7) * 16);
                ringIssue(outring + srcBase + (size_t)arow * 256 + Dbase + aj * 4, wv);
            }
            // Bs stage (all 512): colr = tid>>1 (0..255), kp = (tid&1)*16
            {
                const int colr = tid >> 1, kp = (tid & 1) * 16;
                const size_t wrow = (size_t)(ph * 256 + colr) * HID + kk + kp;
                if (f32) {
                    BF8 u0, u1;
#pragma unroll
                    for (int i = 0; i < 8; ++i) {
                        u0.u[i] = f2bfbits(((const float*)Wih1)[wrow + i]);
                        u1.u[i] = f2bfbits(((const float*)Wih1)[wrow + 8 + i]);
                    }
                    *(bf16x8*)&Bs[colr * 32 + kp] = u0.v;
                    *(bf16x8*)&Bs[colr * 32 + kp + 8] = u1.v;
                } else {
                    *(bf16x8*)&Bs[colr * 32 + kp] =
                        *(const bf16x8*)((const __hip_bfloat16*)Wih1 + wrow);
                    *(bf16x8*)&Bs[colr * 32 + kp + 8] =
                        *(const bf16x8*)((const __hip_bfloat16*)Wih1 + wrow + 8);
                }
            }
            if (tid < 256) {
                ringWait(wv);
                BF4 lo, hi;
#pragma unroll
                for (int i = 0; i < 4; ++i) {
                    lo.u[i] = (unsigned short)(wv[i] & 0xffffu);
                    hi.u[i] = (unsigned short)(wv[i] >> 16);
                }
                *(bf16x4*)&As[arow * 32 + aj * 4] = lo.v;
                *(bf16x4*)&As[arow * 32 + 16 + aj * 4] = hi.v;
            }
            __syncthreads();
            // MFMA: wave covers cols ph*256 + wave*32 + tau*16 + l15
            bf16x8 b0 = *(const bf16x8*)&Bs[(wave * 32 + l15) * 32 + q * 8];
            bf16x8 b1f = *(const bf16x8*)&Bs[(wave * 32 + 16 + l15) * 32 + q * 8];
#pragma unroll
            for (int m = 0; m < 4; ++m) {
                bf16x8 a = *(const bf16x8*)&As[(m * 16 + l15) * 32 + q * 8];
                acc[0][m] = __builtin_amdgcn_mfma_f32_16x16x32_bf16(a, b0, acc[0][m], 0, 0, 0);
                acc[1][m] = __builtin_amdgcn_mfma_f32_16x16x32_bf16(a, b1f, acc[1][m], 0, 0, 0);
            }
            __syncthreads();
        }

        // epilogue: bias + pack (col, col+16) + ring store
        const int col0 = ph * 256 + wave * 32 + l15;
        const int col1 = col0 + 16;
        float bias0 = loadE(b1, col0, f32) + loadE(b2, col0, f32);
        float bias1 = loadE(b1, col1, f32) + loadE(b2, col1, f32);
        const int Dst = ph * 128 + wave * 16 + l15;
        const size_t dstBase = ((size_t)(t % R1SLOTS) * 128 + nh * 64) * 256;
#pragma unroll
        for (int m = 0; m < 4; ++m)
#pragma unroll
            for (int r = 0; r < 4; ++r) {
                unsigned int pk = (unsigned int)f2bfbits(acc[0][m][r] + bias0)
                                | ((unsigned int)f2bfbits(acc[1][m][r] + bias1) << 16);
                astore(&xp1ring[dstBase + (size_t)(m * 16 + q * 4 + r) * 256 + Dst], pk);
            }
        asm volatile("s_waitcnt vmcnt(0)" ::: "memory");
        __syncthreads();
        if (tid == 0) astore(&F[(size_t)t * 4 + nh * 2 + ph], (unsigned int)(t + 1));
    }
}

// ---------------- fused kernel: 16 L0 + 16 L1 + NWORKER workers
__global__ __launch_bounds__(512, 2) void rnn_fused(
    const __hip_bfloat16* __restrict__ xp0,
    const void* __restrict__ Whh0, const void* __restrict__ Whh1,
    const void* __restrict__ Wih1, const void* __restrict__ bih1, const void* __restrict__ bhh1,
    const void* __restrict__ h0all, const int* __restrict__ lengths,
    unsigned int* __restrict__ outring, unsigned int* __restrict__ xp1ring,
    void* __restrict__ hout, __hip_bfloat16* __restrict__ hfbf,
    unsigned int* __restrict__ ex, const unsigned int* __restrict__ dflag,
    unsigned int* __restrict__ syncw)
{
    __shared__ short smem[2 * HB];   // 32 KB
    unsigned int* c0w = syncw;                 // 32 words
    unsigned int* F   = syncw + 32;            // 2048 words
    unsigned int* c1w = syncw + 32 + 2048;     // 32 words
    const int bid = blockIdx.x, tid = threadIdx.x;
    if (bid < 16) {
        recur_role(bid, tid, smem, xp0, Whh0, h0all, 0, lengths, outring, xp1ring,
                   hout, NBATCH * 128, hfbf, ex, dflag, c0w, F, c1w);
    } else if (bid < 32) {
        recur_role(bid - 16, tid, smem, nullptr, Whh1, h0all, 1, lengths, outring, xp1ring,
                   hout, NBATCH * 128 + NBATCH * HID, hfbf + (size_t)NBATCH * HID,
                   ex + EX_WORDS, dflag, c0w, F, c1w);
    } else {
        worker_role(bid - 32, tid, smem, Wih1, bih1, bhh1, lengths,
                    outring, xp1ring, dflag, c0w, F, c1w);
    }
}

extern "C" void kernel_launch(void* const* d_in, const int* in_sizes, int n_in,
                              void* d_out, int out_size, void* d_ws, size_t ws_size,
                              hipStream_t stream) {
    const void* x    = d_in[0];
    const void* h0   = d_in[1];
    const int*  lens = (const int*)d_in[2];
    const void* Wih0 = d_in[3];
    const void* bih0 = d_in[4];
    const void* Whh0 = d_in[5];
    const void* bhh0 = d_in[6];
    const void* Wih1 = d_in[7];
    const void* bih1 = d_in[8];
    const void* Whh1 = d_in[9];
    const void* bhh1 = d_in[10];
    const void* Wfc  = d_in[11];
    const void* bfc  = d_in[12];

    const size_t MROWS = (size_t)T_STEPS * NBATCH;          // 65536
    size_t off = 0;
    auto take = [&](size_t bytes) { size_t o = off; off += (bytes + 255) & ~255ull; return o; };
    const size_t off_xp   = take(MROWS * HID * 2);                         // xp0: 64 MB
    const size_t off_or   = take((size_t)R0SLOTS * NBATCH * 256 * 4);     // out0 ring: 8 MB
    const size_t off_xr   = take((size_t)R1SLOTS * NBATCH * 256 * 4);     // xp1 ring: 4 MB
    const size_t off_ex   = take(2 * (size_t)EX_WORDS * 4);               // 1 MB
    const size_t off_hfbf = take(2ull * NBATCH * HID * 2);                // 256 KB
    const size_t off_sync = take(16384);                                  // flags/counters
    const size_t off_dfl  = take(256);
    if (ws_size < off) return;  // workspace too small

    char* ws = (char*)d_ws;
    __hip_bfloat16* xp0   = (__hip_bfloat16*)(ws + off_xp);
    unsigned int* outring = (unsigned int*)(ws + off_or);
    unsigned int* xp1ring = (unsigned int*)(ws + off_xr);
    unsigned int* ex      = (unsigned int*)(ws + off_ex);
    __hip_bfloat16* hfbf  = (__hip_bfloat16*)(ws + off_hfbf);
    unsigned int* syncw   = (unsigned int*)(ws + off_sync);
    unsigned int* dflag   = (unsigned int*)(ws + off_dfl);

    // zero flags/counters (required: stale "done" state would break gating).
    hipMemsetAsync(syncw, 0, 16384, stream);
    detect_dtype<<<1, 64, 0, stream>>>((const unsigned short*)x, dflag);

    // xp0 = x @ Wih0^T + bih0 + bhh0  (precomputed for all t)
    gemm_bt64<<<dim3(HID / 64, MROWS / 64), 256, 0, stream>>>(
        x, Wih0, bih0, bhh0, xp0, (int)MROWS, HID, INSZ, lens, dflag, 1, 0);

    // fused: L0 recur || xp1 GEMM workers || L1 recur
    rnn_fused<<<32 + NWORKER, 512, 0, stream>>>(
        xp0, Whh0, Whh1, Wih1, bih1, bhh1, h0, lens,
        outring, xp1ring, d_out, hfbf, ex, dflag, syncw);

    // logits = h1_final @ Wfc^T + bfc
    gemm_bt64<<<dim3(2, 2), 256, 0, stream>>>(
        hfbf + (size_t)NBATCH * HID, Wfc, bfc, nullptr,
        d_out, NBATCH, 128, HID, nullptr, dflag, 0, 1);
}

// Round 13
// 1341.566 us; speedup vs baseline: 1.0334x; 1.0334x over previous
//
#include <hip/hip_runtime.h>
#include <hip/hip_bf16.h>

// R18 = R17/R13 with NWORKER 64 -> 40 (single-variable contention experiment).
// Rationale: fused kernel is latency-bound on the per-step exchange polls
// (L3 round-trips); 64 worker blocks are ~8x over-provisioned for the xp1 tile
// rate (1.7 tiles/us needed; each tile ~2us) and their concurrent ring traffic
// lengthens L3 queues on the poll path. Fewer concurrent workers = shorter L3
// queues; schedule/gating are NWORKER-independent so correctness is preserved.
// R13: fused pipeline -- blocks 0-15 L0 recurrence (R9 split-K step structure),
// blocks 16-31 L1 recurrence, blocks 32+ persistent GEMM workers computing
// xp1 = out0 @ Wih1^T tiles as L0 produces out0 rows. Cross-block dataflow via
// L3-resident rings (out0 64 rows, xp1 32 rows, packed (col,col+16) dwords,
// agent-scope atomics); readiness via monotonic counters/flags ordered by each
// wave's vmcnt(0)+barrier.

typedef __attribute__((ext_vector_type(8))) short bf16x8;
typedef __attribute__((ext_vector_type(4))) short bf16x4;
typedef __attribute__((ext_vector_type(4))) float f32x4;
typedef __attribute__((ext_vector_type(4))) unsigned int u32x4;

#define T_STEPS 512
#define NBATCH  128
#define HID     512
#define INSZ    256
#define HB      8192      // shorts per LDS h buffer (16 samples x 512 cols, frag-major)
#define R0SLOTS 64        // out0 ring rows
#define R1SLOTS 32        // xp1 ring rows
#define EX_WORDS 131072   // 8 gb x 2 slot x 2 p x 4096
#define NWORKER 40

static __device__ __forceinline__ float bf2f(__hip_bfloat16 v) { return __bfloat162float(v); }
static __device__ __forceinline__ __hip_bfloat16 f2bf(float v) { return __float2bfloat16(v); }

union BF8 { bf16x8 v; unsigned short u[8]; };
union BF4 { bf16x4 v; unsigned short u[4]; };
static __device__ __forceinline__ unsigned short f2bfbits(float x) {
    __hip_bfloat16 b = __float2bfloat16(x);
    return *reinterpret_cast<unsigned short*>(&b);
}
static __device__ __forceinline__ float bfbits2f(unsigned short us) {
    return bf2f(*reinterpret_cast<__hip_bfloat16*>(&us));
}
static __device__ __forceinline__ float loadE(const void* p, size_t i, bool f32) {
    return f32 ? ((const float*)p)[i] : bf2f(((const __hip_bfloat16*)p)[i]);
}
// tanh(x) = 1 - 2/(e^{2x}+1); exp over/underflow saturates correctly to +-1.
static __device__ __forceinline__ float fast_tanh(float x) {
    float e = __expf(2.f * x);
    float r = __builtin_amdgcn_rcpf(e + 1.f);
    return 1.f - 2.f * r;
}
static __device__ __forceinline__ unsigned int aload(const unsigned int* p) {
    return __hip_atomic_load(p, __ATOMIC_RELAXED, __HIP_MEMORY_SCOPE_AGENT);
}
static __device__ __forceinline__ void astore(unsigned int* p, unsigned int v) {
    __hip_atomic_store(p, v, __ATOMIC_RELAXED, __HIP_MEMORY_SCOPE_AGENT);
}
// coherent reload + full drain (retry path only)
static __device__ __forceinline__ void load2_coherent(const unsigned int* p, u32x4& a, u32x4& b) {
    asm volatile("global_load_dwordx4 %0, %2, off sc0 sc1\n\t"
                 "global_load_dwordx4 %1, %3, off sc0 sc1\n\t"
                 "s_waitcnt vmcnt(0)"
                 : "=&v"(a), "=&v"(b)
                 : "v"(p), "v"(p + 4)
                 : "memory");
}
// issue poll loads early (no wait)
static __device__ __forceinline__ void pollIssue(const unsigned int* p, u32x4& a, u32x4& b) {
    asm volatile("global_load_dwordx4 %0, %2, off sc0 sc1\n\t"
                 "global_load_dwordx4 %1, %3, off sc0 sc1"
                 : "=&v"(a), "=&v"(b)
                 : "v"(p), "v"(p + 4)
                 : "memory");
}
// full-drain wait; consumers data-depend on in-out operands (rule-18 safe)
static __device__ __forceinline__ void pollWait(u32x4& a, u32x4& b) {
    asm volatile("s_waitcnt vmcnt(0)" : "+v"(a), "+v"(b) :: "memory");
}
// coherent 16B ring load: issue-only + wait-later pair
static __device__ __forceinline__ void ringIssue(const unsigned int* p, u32x4& w) {
    asm volatile("global_load_dwordx4 %0, %1, off sc0 sc1"
                 : "=&v"(w) : "v"(p) : "memory");
}
static __device__ __forceinline__ void ringWait(u32x4& w) {
    asm volatile("s_waitcnt vmcnt(0)" : "+v"(w) :: "memory");
}

// ---------------- dtype probe
__global__ void detect_dtype(const unsigned short* __restrict__ x, unsigned int* __restrict__ dflag) {
    if (threadIdx.x == 0 && blockIdx.x == 0) {
        int sane = 0;
        for (int i = 0; i < 64; ++i) {
            unsigned short v = x[2 * i];
            unsigned int e = (v >> 7) & 0xFF;
            if (v == 0 || (e >= 0x60 && e <= 0x9F)) ++sane;
        }
        *dflag = (sane >= 48) ? 0u : 1u;  // 0 = bf16 data, 1 = fp32 data
    }
}

// ---------------- GEMM: out[M][N] = A[M][K] @ W[N][K]^T + b1[N] (+ b2[N])
__global__ __launch_bounds__(256, 4) void gemm_bt64(
    const void* __restrict__ A, const void* __restrict__ W,
    const void* __restrict__ b1, const void* __restrict__ b2,
    void* __restrict__ out, int M, int N, int K,
    const int* __restrict__ lengths, const unsigned int* __restrict__ dflag,
    int aIsOrig, int outIsOutput)
{
    const int r0 = blockIdx.y * 64;
    if (lengths) {
        int t = r0 >> 7, n0 = r0 & 127;
        if (lengths[n0] <= t) return;
    }
    const bool f32 = *dflag != 0;
    const int c0 = blockIdx.x * 64;
    __shared__ short As[64 * 32];
    __shared__ short Bs[64 * 32];
    const int tid = threadIdx.x;
    const int lane = tid & 63, wave = tid >> 6;
    const int lrow = tid >> 2, lk = (tid & 3) * 8;
    const int q = (lane >> 4) & 3, l15 = lane & 15;

    f32x4 z = {0.f, 0.f, 0.f, 0.f};
    f32x4 acc[4];
#pragma unroll
    for (int m = 0; m < 4; ++m) acc[m] = z;

    for (int kk = 0; kk < K; kk += 32) {
        if (aIsOrig && f32) {
            const float* f = (const float*)A + (size_t)(r0 + lrow) * K + kk + lk;
            BF8 u;
#pragma unroll
            for (int i = 0; i < 8; ++i) u.u[i] = f2bfbits(f[i]);
            *(bf16x8*)&As[lrow * 32 + lk] = u.v;
        } else {
            *(bf16x8*)&As[lrow * 32 + lk] =
                *(const bf16x8*)((const __hip_bfloat16*)A + (size_t)(r0 + lrow) * K + kk + lk);
        }
        if (f32) {
            const float* f = (const float*)W + (size_t)(c0 + lrow) * K + kk + lk;
            BF8 u;
#pragma unroll
            for (int i = 0; i < 8; ++i) u.u[i] = f2bfbits(f[i]);
            *(bf16x8*)&Bs[lrow * 32 + lk] = u.v;
        } else {
            *(bf16x8*)&Bs[lrow * 32 + lk] =
                *(const bf16x8*)((const __hip_bfloat16*)W + (size_t)(c0 + lrow) * K + kk + lk);
        }
        __syncthreads();
        bf16x8 bfrag = *(const bf16x8*)&Bs[(wave * 16 + l15) * 32 + q * 8];
#pragma unroll
        for (int m = 0; m < 4; ++m) {
            bf16x8 afrag = *(const bf16x8*)&As[(m * 16 + l15) * 32 + q * 8];
            acc[m] = __builtin_amdgcn_mfma_f32_16x16x32_bf16(afrag, bfrag, acc[m], 0, 0, 0);
        }
        __syncthreads();
    }
    const int col = c0 + wave * 16 + l15;
    float bias = loadE(b1, col, f32) + (b2 ? loadE(b2, col, f32) : 0.f);
#pragma unroll
    for (int m = 0; m < 4; ++m) {
#pragma unroll
        for (int r = 0; r < 4; ++r) {
            int row = r0 + m * 16 + q * 4 + r;
            float v = acc[m][r] + bias;
            if (outIsOutput && f32) ((float*)out)[(size_t)row * N + col] = v;
            else ((__hip_bfloat16*)out)[(size_t)row * N + col] = f2bf(v);
        }
    }
}

// ---------------- recurrence role (R9 step structure + ring/flag deltas)
static __device__ void recur_role(
    int rbid, int tid, short* hlds,
    const __hip_bfloat16* __restrict__ xp0,
    const void* __restrict__ Whh, const void* __restrict__ h0all, int layer,
    const int* __restrict__ lengths,
    unsigned int* __restrict__ outring, unsigned int* __restrict__ xp1ring,
    void* __restrict__ hout, int houtOff, __hip_bfloat16* __restrict__ hfbf,
    unsigned int* __restrict__ ex, const unsigned int* __restrict__ dflag,
    unsigned int* __restrict__ c0w, unsigned int* __restrict__ F,
    unsigned int* __restrict__ c1w)
{
    const int gb = rbid & 7, p = (rbid >> 3) & 1;
    const int lane = tid & 63, wave = tid >> 6;
    const int q = (lane >> 4) & 3, l15 = lane & 15;
    const int colBase = p * 256 + wave * 32;
    const int s0 = gb * 16;
    const int nh = gb >> 2;
    const int pcPart = (1 - p) * 256;
    const int Dr = p * 128 + wave * 16 + l15;   // ring dword index (cols c, c+16)
    const bool f32 = *dflag != 0;
    const size_t h0base = (size_t)layer * NBATCH * HID;

    // persistent B fragments, STATIC indices only (rule #20)
    bf16x8 bfr_own[2][8], bfr_par[2][8];
    {
        const int kbO = p * 256, kbP = (1 - p) * 256;
#pragma unroll
        for (int tau = 0; tau < 2; ++tau) {
            const size_t jrow = (size_t)(colBase + tau * 16 + l15) * HID;
            if (f32) {
#pragma unroll
                for (int c8 = 0; c8 < 8; ++c8) {
                    const float* fo = (const float*)Whh + jrow + kbO + c8 * 32 + q * 8;
                    const float* fp = (const float*)Whh + jrow + kbP + c8 * 32 + q * 8;
                    BF8 uo, up;
#pragma unroll
                    for (int i = 0; i < 8; ++i) { uo.u[i] = f2bfbits(fo[i]); up.u[i] = f2bfbits(fp[i]); }
                    bfr_own[tau][c8] = uo.v; bfr_par[tau][c8] = up.v;
                }
            } else {
#pragma unroll
                for (int c8 = 0; c8 < 8; ++c8) {
                    bfr_own[tau][c8] = *(const bf16x8*)((const __hip_bfloat16*)Whh + jrow + kbO + c8 * 32 + q * 8);
                    bfr_par[tau][c8] = *(const bf16x8*)((const __hip_bfloat16*)Whh + jrow + kbP + c8 * 32 + q * 8);
                }
            }
        }
    }

    int len_r[4];
#pragma unroll
    for (int r = 0; r < 4; ++r) len_r[r] = lengths[s0 + q * 4 + r];

    float cur[2][4];
#pragma unroll
    for (int tau = 0; tau < 2; ++tau)
#pragma unroll
        for (int r = 0; r < 4; ++r)
            cur[tau][r] = loadE(h0all, h0base + (size_t)(s0 + q * 4 + r) * HID + colBase + tau * 16 + l15, f32);

    // stage FULL S_0 into LDS buf 0 (frag-major)
    {
        const int sr = tid >> 5, cb16 = (tid & 31) * 16;
        BF8 u0, u1;
#pragma unroll
        for (int i = 0; i < 8; ++i) {
            u0.u[i] = f2bfbits(loadE(h0all, h0base + (size_t)(s0 + sr) * HID + cb16 + i, f32));
            u1.u[i] = f2bfbits(loadE(h0all, h0base + (size_t)(s0 + sr) * HID + cb16 + 8 + i, f32));
        }
        *(bf16x8*)&hlds[(((cb16 >> 3) * 16) + sr) * 8] = u0.v;
        *(bf16x8*)&hlds[((((cb16 + 8) >> 3) * 16) + sr) * 8] = u1.v;
    }
    __syncthreads();

    const int Tg = lengths[s0];
    const int psr = tid >> 5;
    const int pwc = (tid * 8) & 255;
    unsigned int* exg = ex + (size_t)gb * 2 * 2 * 4096;

    // xp prologue (row 0)
    float xv[2][4];
    unsigned int l1flag = 0;
    if (layer == 0) {
        const __hip_bfloat16* xprow = xp0 + (size_t)s0 * HID;
#pragma unroll
        for (int tau = 0; tau < 2; ++tau)
#pragma unroll
            for (int r = 0; r < 4; ++r)
                xv[tau][r] = bf2f(xprow[(size_t)(q * 4 + r) * HID + colBase + tau * 16 + l15]);
    } else {
        const unsigned int* fp = &F[(size_t)nh * 2 + p];   // row 0 flag
        int spins = 0;
        while (aload(fp) != 1u) {
            __builtin_amdgcn_s_sleep(2);
            if (++spins > (1 << 20)) break;
        }
#pragma unroll
        for (int r = 0; r < 4; ++r) {
            unsigned int u = aload(&xp1ring[((size_t)(s0 + q * 4 + r)) * 256 + Dr]);
            xv[0][r] = bfbits2f((unsigned short)(u & 0xffffu));
            xv[1][r] = bfbits2f((unsigned short)(u >> 16));
        }
        if (1 < Tg) l1flag = aload(&F[(size_t)1 * 4 + nh * 2 + p]);
    }

    for (int t = 0; t < Tg; ++t) {
        const int cb = t & 1, nb = (t + 1) & 1;
        short* hrd = &hlds[cb * HB];
        short* hwr = &hlds[nb * HB];
        const unsigned int ptag = (unsigned int)t;

        // L0 back-pressure on out0 ring (amortized; wave 0 only, sync1 fences)
        if (layer == 0 && t >= R0SLOTS && (t & 15) == 0 && wave == 0) {
            const int row = t - R0SLOTS + ((lane >> 1) & 15);
            const unsigned int* fp = &F[(size_t)row * 4 + nh * 2 + (lane & 1)];
            const unsigned int expv = (unsigned int)(row + 1);
            int spins = 0;
            while (!__all((int)(aload(fp) == expv))) {
                __builtin_amdgcn_s_sleep(2);
                if (++spins > (1 << 20)) break;
            }
        }

        // xp prefetch for row t+1
        float xn[2][4];
        unsigned int xnu[4];
        if (t + 1 < Tg) {
            if (layer == 0) {
                const __hip_bfloat16* xprow = xp0 + ((size_t)(t + 1) * NBATCH + s0) * HID;
#pragma unroll
                for (int tau = 0; tau < 2; ++tau)
#pragma unroll
                    for (int r = 0; r < 4; ++r)
                        xn[tau][r] = bf2f(xprow[(size_t)(q * 4 + r) * HID + colBase + tau * 16 + l15]);
            } else {
                const unsigned int expv = (unsigned int)(t + 2);
                if (l1flag != expv) {
                    const unsigned int* fp = &F[(size_t)(t + 1) * 4 + nh * 2 + p];
                    int spins = 0;
                    while (aload(fp) != expv) {
                        __builtin_amdgcn_s_sleep(1);
                        if (++spins > (1 << 20)) break;
                    }
                }
                const size_t rb = ((size_t)((t + 1) % R1SLOTS) * 128 + s0) * 256;
#pragma unroll
                for (int r = 0; r < 4; ++r)
                    xnu[r] = aload(&xp1ring[rb + (size_t)(q * 4 + r) * 256 + Dr]);
            }
        }

        // poll loads for partner half of S_t
        const unsigned int* exr = exg + ((size_t)cb * 2 + (1 - p)) * 4096 + tid * 8;
        u32x4 va, vb;
        if (t > 0) pollIssue(exr, va, vb);

        f32x4 zz = {0.f, 0.f, 0.f, 0.f};
        f32x4 acc[2] = {zz, zz};

        // (a) own k-half MFMA
        {
            const int cO = p * 8;
#pragma unroll
            for (int c8 = 0; c8 < 8; ++c8) {
                bf16x8 a = *(const bf16x8*)&hrd[(((cO + c8) * 4 + q) * 16 + l15) * 8];
                acc[0] = __builtin_amdgcn_mfma_f32_16x16x32_bf16(a, bfr_own[0][c8], acc[0], 0, 0, 0);
                acc[1] = __builtin_amdgcn_mfma_f32_16x16x32_bf16(a, bfr_own[1][c8], acc[1], 0, 0, 0);
            }
        }

        // (b) poll partner's half of S_t; write into hrd partner region
        if (t > 0) {
            pollWait(va, vb);
            int spins = 0;
            for (;;) {
                bool ok = (va[0] >> 16) == ptag && (va[1] >> 16) == ptag &&
                          (va[2] >> 16) == ptag && (va[3] >> 16) == ptag &&
                          (vb[0] >> 16) == ptag && (vb[1] >> 16) == ptag &&
                          (vb[2] >> 16) == ptag && (vb[3] >> 16) == ptag;
                if (ok) break;
                if (++spins > 4) __builtin_amdgcn_s_sleep(1);
                if (spins > (1 << 20)) break;
                load2_coherent(exr, va, vb);
            }
            BF8 u;
            u.u[0] = (unsigned short)(va[0] & 0xFFFF); u.u[1] = (unsigned short)(va[1] & 0xFFFF);
            u.u[2] = (unsigned short)(va[2] & 0xFFFF); u.u[3] = (unsigned short)(va[3] & 0xFFFF);
            u.u[4] = (unsigned short)(vb[0] & 0xFFFF); u.u[5] = (unsigned short)(vb[1] & 0xFFFF);
            u.u[6] = (unsigned short)(vb[2] & 0xFFFF); u.u[7] = (unsigned short)(vb[3] & 0xFFFF);
            const int jp = pcPart + pwc;
            *(bf16x8*)&hrd[((jp >> 3) * 16 + psr) * 8] = u.v;
        }
        __syncthreads();   // sync1

        // progress publish (ordering: every wave's (b) vmcnt(0) + barrier above)
        if (t > 0 && tid == 0) {
            if (layer == 0) astore(&c0w[gb * 2 + p], (unsigned int)t);
            else            astore(&c1w[gb * 2 + p], (unsigned int)(t + 2));
        }
        if (layer == 1 && t + 2 < Tg)
            l1flag = aload(&F[(size_t)(t + 2) * 4 + nh * 2 + p]);

        // (c) partner k-half MFMA
        {
            const int cP = (1 - p) * 8;
#pragma unroll
            for (int c8 = 0; c8 < 8; ++c8) {
                bf16x8 a = *(const bf16x8*)&hrd[(((cP + c8) * 4 + q) * 16 + l15) * 8];
                acc[0] = __builtin_amdgcn_mfma_f32_16x16x32_bf16(a, bfr_par[0][c8], acc[0], 0, 0, 0);
                acc[1] = __builtin_amdgcn_mfma_f32_16x16x32_bf16(a, bfr_par[1][c8], acc[1], 0, 0, 0);
            }
        }

        // (d) tanh; publish own half of S_{t+1}; out0 ring (layer 0); LDS h write
        const unsigned int tag = (unsigned int)(t + 1);
        unsigned int* exw = exg + ((size_t)nb * 2 + p) * 4096;
        unsigned short bits[2][4];
#pragma unroll
        for (int tau = 0; tau < 2; ++tau)
#pragma unroll
            for (int r = 0; r < 4; ++r) {
                float hnew = fast_tanh(acc[tau][r] + xv[tau][r]);
                float val = (t < len_r[r]) ? hnew : cur[tau][r];
                cur[tau][r] = val;
                bits[tau][r] = f2bfbits(val);
                if (t + 1 < Tg)
                    __hip_atomic_store(&exw[(q * 4 + r) * 256 + wave * 32 + tau * 16 + l15],
                                       (tag << 16) | (unsigned int)bits[tau][r],
                                       __ATOMIC_RELAXED, __HIP_MEMORY_SCOPE_AGENT);
            }
        if (layer == 0) {
            const size_t rb = ((size_t)(t % R0SLOTS) * 128 + s0) * 256;
#pragma unroll
            for (int r = 0; r < 4; ++r) {
                unsigned int pk = (unsigned int)bits[0][r] | ((unsigned int)bits[1][r] << 16);
                astore(&outring[rb + (size_t)(q * 4 + r) * 256 + Dr], pk);
            }
        }
#pragma unroll
        for (int tau = 0; tau < 2; ++tau)
#pragma unroll
            for (int r = 0; r < 4; ++r) {
                const int sl = q * 4 + r;
                const int j = colBase + tau * 16 + l15;
                hwr[((j >> 3) * 16 + sl) * 8 + (j & 7)] = (short)bits[tau][r];
            }
        __syncthreads();   // sync2

        if (t + 1 < Tg) {
            if (layer == 0) {
#pragma unroll
                for (int tau = 0; tau < 2; ++tau)
#pragma unroll
                    for (int r = 0; r < 4; ++r) xv[tau][r] = xn[tau][r];
            } else {
#pragma unroll
                for (int r = 0; r < 4; ++r) {
                    xv[0][r] = bfbits2f((unsigned short)(xnu[r] & 0xffffu));
                    xv[1][r] = bfbits2f((unsigned short)(xnu[r] >> 16));
                }
            }
        }
    }

    // finalize counters (rows all at coherence point)
    asm volatile("s_waitcnt vmcnt(0)" ::: "memory");
    __syncthreads();
    if (tid == 0) {
        if (layer == 0) astore(&c0w[gb * 2 + p], 1u << 20);
        else            astore(&c1w[gb * 2 + p], 1u << 20);
    }

    // finals: h to d_out + bf16 copy for logits GEMM
#pragma unroll
    for (int tau = 0; tau < 2; ++tau)
#pragma unroll
        for (int r = 0; r < 4; ++r) {
            size_t idx = (size_t)(s0 + q * 4 + r) * HID + colBase + tau * 16 + l15;
            if (f32) ((float*)hout)[houtOff + idx] = cur[tau][r];
            else     ((__hip_bfloat16*)hout)[houtOff + idx] = f2bf(cur[tau][r]);
            hfbf[idx] = f2bf(cur[tau][r]);
        }
}

// ---------------- worker role: xp1 tiles (64 rows x 256 cols), streaming K
static __device__ void worker_role(
    int wid, int tid, short* smem,
    const void* __restrict__ Wih1, const void* __restrict__ b1, const void* __restrict__ b2,
    const int* __restrict__ lengths,
    unsigned int* __restrict__ outring, unsigned int* __restrict__ xp1ring,
    const unsigned int* __restrict__ dflag,
    unsigned int* __restrict__ c0w, unsigned int* __restrict__ F,
    unsigned int* __restrict__ c1w)
{
    const bool f32 = *dflag != 0;
    const int lane = tid & 63, wave = tid >> 6;
    const int q = (lane >> 4) & 3, l15 = lane & 15;
    short* As = smem;           // 64 x 32
    short* Bs = smem + 2048;    // 256 x 32
    const int len0 = lengths[0], len64 = lengths[64];

    for (int lin = wid; lin < T_STEPS * 4; lin += NWORKER) {
        const int t = lin >> 2, nh = (lin >> 1) & 1, ph = lin & 1;
        const int lenh = nh ? len64 : len0;
        if (lenh <= t) continue;   // dead tile (uniform)

        // ready gate: wave 0 spins; other waves wait at the barrier
        if (wave == 0) {
            const int gbase = nh * 4;
            int spins = 0;
            for (;;) {
                bool ok = true;
#pragma unroll
                for (int g = 0; g < 4; ++g) {
                    ok = ok && ((int)aload(&c0w[(gbase + g) * 2 + 0]) >= t + 1);
                    ok = ok && ((int)aload(&c0w[(gbase + g) * 2 + 1]) >= t + 1);
                }
                if (t >= R1SLOTS) {
#pragma unroll
                    for (int g = 0; g < 4; ++g)
                        ok = ok && ((int)aload(&c1w[(gbase + g) * 2 + ph]) >= t - R1SLOTS + 1);
                }
                if (ok) break;
                __builtin_amdgcn_s_sleep(8);
                if (++spins > (1 << 20)) break;
            }
        }
        __syncthreads();

        f32x4 z = {0.f, 0.f, 0.f, 0.f};
        f32x4 acc[2][4];
#pragma unroll
        for (int tau = 0; tau < 2; ++tau)
#pragma unroll
            for (int m = 0; m < 4; ++m) acc[tau][m] = z;

        const size_t srcBase = ((size_t)(t % R0SLOTS) * 128 + nh * 64) * 256;
        const int arow = tid >> 2, aj = tid & 3;   // As staging map (tid<256)

        for (int kk = 0; kk < HID; kk += 32) {
            // As: issue ONE contiguous dwordx4 per thread (16 dwords per row =
            // the full 32-col chunk; lo half = cols kk+c15, hi = kk+16+c15)
            u32x4 wv;
            if (tid < 256) {   // waves 0-3 (wave-uniform branch)
                const int Dbase = ((kk >> 8) * 128) + (((kk >> 5) & 7) * 16);
                ringIssue(outring + srcBase + (size_t)arow * 256 + Dbase + aj * 4, wv);
            }
            // Bs stage (all 512): colr = tid>>1 (0..255), kp = (tid&1)*16
            {
                const int colr = tid >> 1, kp = (tid & 1) * 16;
                const size_t wrow = (size_t)(ph * 256 + colr) * HID + kk + kp;
                if (f32) {
                    BF8 u0, u1;
#pragma unroll
                    for (int i = 0; i < 8; ++i) {
                        u0.u[i] = f2bfbits(((const float*)Wih1)[wrow + i]);
                        u1.u[i] = f2bfbits(((const float*)Wih1)[wrow + 8 + i]);
                    }
                    *(bf16x8*)&Bs[colr * 32 + kp] = u0.v;
                    *(bf16x8*)&Bs[colr * 32 + kp + 8] = u1.v;
                } else {
                    *(bf16x8*)&Bs[colr * 32 + kp] =
                        *(const bf16x8*)((const __hip_bfloat16*)Wih1 + wrow);
                    *(bf16x8*)&Bs[colr * 32 + kp + 8] =
                        *(const bf16x8*)((const __hip_bfloat16*)Wih1 + wrow + 8);
                }
            }
            if (tid < 256) {
                ringWait(wv);
                BF4 lo, hi;
#pragma unroll
                for (int i = 0; i < 4; ++i) {
                    lo.u[i] = (unsigned short)(wv[i] & 0xffffu);
                    hi.u[i] = (unsigned short)(wv[i] >> 16);
                }
                *(bf16x4*)&As[arow * 32 + aj * 4] = lo.v;
                *(bf16x4*)&As[arow * 32 + 16 + aj * 4] = hi.v;
            }
            __syncthreads();
            // MFMA: wave covers cols ph*256 + wave*32 + tau*16 + l15
            bf16x8 b0 = *(const bf16x8*)&Bs[(wave * 32 + l15) * 32 + q * 8];
            bf16x8 b1f = *(const bf16x8*)&Bs[(wave * 32 + 16 + l15) * 32 + q * 8];
#pragma unroll
            for (int m = 0; m < 4; ++m) {
                bf16x8 a = *(const bf16x8*)&As[(m * 16 + l15) * 32 + q * 8];
                acc[0][m] = __builtin_amdgcn_mfma_f32_16x16x32_bf16(a, b0, acc[0][m], 0, 0, 0);
                acc[1][m] = __builtin_amdgcn_mfma_f32_16x16x32_bf16(a, b1f, acc[1][m], 0, 0, 0);
            }
            __syncthreads();
        }

        // epilogue: bias + pack (col, col+16) + ring store
        const int col0 = ph * 256 + wave * 32 + l15;
        const int col1 = col0 + 16;
        float bias0 = loadE(b1, col0, f32) + loadE(b2, col0, f32);
        float bias1 = loadE(b1, col1, f32) + loadE(b2, col1, f32);
        const int Dst = ph * 128 + wave * 16 + l15;
        const size_t dstBase = ((size_t)(t % R1SLOTS) * 128 + nh * 64) * 256;
#pragma unroll
        for (int m = 0; m < 4; ++m)
#pragma unroll
            for (int r = 0; r < 4; ++r) {
                unsigned int pk = (unsigned int)f2bfbits(acc[0][m][r] + bias0)
                                | ((unsigned int)f2bfbits(acc[1][m][r] + bias1) << 16);
                astore(&xp1ring[dstBase + (size_t)(m * 16 + q * 4 + r) * 256 + Dst], pk);
            }
        asm volatile("s_waitcnt vmcnt(0)" ::: "memory");
        __syncthreads();
        if (tid == 0) astore(&F[(size_t)t * 4 + nh * 2 + ph], (unsigned int)(t + 1));
    }
}

// ---------------- fused kernel: 16 L0 + 16 L1 + NWORKER workers
__global__ __launch_bounds__(512, 2) void rnn_fused(
    const __hip_bfloat16* __restrict__ xp0,
    const void* __restrict__ Whh0, const void* __restrict__ Whh1,
    const void* __restrict__ Wih1, const void* __restrict__ bih1, const void* __restrict__ bhh1,
    const void* __restrict__ h0all, const int* __restrict__ lengths,
    unsigned int* __restrict__ outring, unsigned int* __restrict__ xp1ring,
    void* __restrict__ hout, __hip_bfloat16* __restrict__ hfbf,
    unsigned int* __restrict__ ex, const unsigned int* __restrict__ dflag,
    unsigned int* __restrict__ syncw)
{
    __shared__ short smem[2 * HB];   // 32 KB
    unsigned int* c0w = syncw;                 // 32 words
    unsigned int* F   = syncw + 32;            // 2048 words
    unsigned int* c1w = syncw + 32 + 2048;     // 32 words
    const int bid = blockIdx.x, tid = threadIdx.x;
    if (bid < 16) {
        recur_role(bid, tid, smem, xp0, Whh0, h0all, 0, lengths, outring, xp1ring,
                   hout, NBATCH * 128, hfbf, ex, dflag, c0w, F, c1w);
    } else if (bid < 32) {
        recur_role(bid - 16, tid, smem, nullptr, Whh1, h0all, 1, lengths, outring, xp1ring,
                   hout, NBATCH * 128 + NBATCH * HID, hfbf + (size_t)NBATCH * HID,
                   ex + EX_WORDS, dflag, c0w, F, c1w);
    } else {
        worker_role(bid - 32, tid, smem, Wih1, bih1, bhh1, lengths,
                    outring, xp1ring, dflag, c0w, F, c1w);
    }
}

extern "C" void kernel_launch(void* const* d_in, const int* in_sizes, int n_in,
                              void* d_out, int out_size, void* d_ws, size_t ws_size,
                              hipStream_t stream) {
    const void* x    = d_in[0];
    const void* h0   = d_in[1];
    const int*  lens = (const int*)d_in[2];
    const void* Wih0 = d_in[3];
    const void* bih0 = d_in[4];
    const void* Whh0 = d_in[5];
    const void* bhh0 = d_in[6];
    const void* Wih1 = d_in[7];
    const void* bih1 = d_in[8];
    const void* Whh1 = d_in[9];
    const void* bhh1 = d_in[10];
    const void* Wfc  = d_in[11];
    const void* bfc  = d_in[12];

    const size_t MROWS = (size_t)T_STEPS * NBATCH;          // 65536
    size_t off = 0;
    auto take = [&](size_t bytes) { size_t o = off; off += (bytes + 255) & ~255ull; return o; };
    const size_t off_xp   = take(MROWS * HID * 2);                         // xp0: 64 MB
    const size_t off_or   = take((size_t)R0SLOTS * NBATCH * 256 * 4);     // out0 ring: 8 MB
    const size_t off_xr   = take((size_t)R1SLOTS * NBATCH * 256 * 4);     // xp1 ring: 4 MB
    const size_t off_ex   = take(2 * (size_t)EX_WORDS * 4);               // 1 MB
    const size_t off_hfbf = take(2ull * NBATCH * HID * 2);                // 256 KB
    const size_t off_sync = take(16384);                                  // flags/counters
    const size_t off_dfl  = take(256);
    if (ws_size < off) return;  // workspace too small

    char* ws = (char*)d_ws;
    __hip_bfloat16* xp0   = (__hip_bfloat16*)(ws + off_xp);
    unsigned int* outring = (unsigned int*)(ws + off_or);
    unsigned int* xp1ring = (unsigned int*)(ws + off_xr);
    unsigned int* ex      = (unsigned int*)(ws + off_ex);
    __hip_bfloat16* hfbf  = (__hip_bfloat16*)(ws + off_hfbf);
    unsigned int* syncw   = (unsigned int*)(ws + off_sync);
    unsigned int* dflag   = (unsigned int*)(ws + off_dfl);

    // zero flags/counters (required: stale "done" state would break gating).
    hipMemsetAsync(syncw, 0, 16384, stream);
    detect_dtype<<<1, 64, 0, stream>>>((const unsigned short*)x, dflag);

    // xp0 = x @ Wih0^T + bih0 + bhh0  (precomputed for all t)
    gemm_bt64<<<dim3(HID / 64, MROWS / 64), 256, 0, stream>>>(
        x, Wih0, bih0, bhh0, xp0, (int)MROWS, HID, INSZ, lens, dflag, 1, 0);

    // fused: L0 recur || xp1 GEMM workers || L1 recur
    rnn_fused<<<32 + NWORKER, 512, 0, stream>>>(
        xp0, Whh0, Whh1, Wih1, bih1, bhh1, h0, lens,
        outring, xp1ring, d_out, hfbf, ex, dflag, syncw);

    // logits = h1_final @ Wfc^T + bfc
    gemm_bt64<<<dim3(2, 2), 256, 0, stream>>>(
        hfbf + (size_t)NBATCH * HID, Wfc, bfc, nullptr,
        d_out, NBATCH, 128, HID, nullptr, dflag, 0, 1);
}